// Round 11
// baseline (295.588 us; speedup 1.0000x reference)
//
#include <hip/hip_runtime.h>

#define NTOK 196
#define NHEAD 12
#define HDIM 64
#define CDIM 768
#define BSZ 64
#define MROWS (BSZ * NTOK)          // 12544
#define PART_STRIDE 9633792         // 64*12*196*64
#define BH_STRIDE 12544             // 196*64
#define VT_LD 224                   // padded key dim for V^T rows (7 k-steps of 32)
#define VT_BH (HDIM * VT_LD)        // 14336
#define PM_H (NTOK * NTOK)          // 38416
#define K2G 6272                    // 196*32: one kk half of K2 in GLOBAL
#define K2HB 12544                  // bytes per kk half in LDS (196*32*2, unpadded+swizzled)

typedef __bf16 bf16x8 __attribute__((ext_vector_type(8)));
typedef float f32x4 __attribute__((ext_vector_type(4)));

static __device__ __forceinline__ unsigned short f_to_bf16(float f) {
    union { float f; unsigned int i; } v; v.f = f;
    unsigned int x = v.i;
    unsigned int r = x + 0x7fffu + ((x >> 16) & 1u);  // RNE
    return (unsigned short)(r >> 16);
}

// async global->LDS, 16 B per lane. LDS dst must be wave-uniform base + lane*16.
static __device__ __forceinline__ void gld16(const unsigned short* g, unsigned short* l) {
    __builtin_amdgcn_global_load_lds(
        (__attribute__((address_space(1))) void*)(unsigned long long)(const void*)g,
        (__attribute__((address_space(3))) void*)(unsigned int)(unsigned long long)(void*)l,
        16, 0, 0);
}

// ---------------- fp32 -> bf16 cast (4 elems/thread) ----------------
__global__ void cvt_f32_bf16(const float* __restrict__ src,
                             unsigned short* __restrict__ dst, int n4) {
    int i = blockIdx.x * 256 + threadIdx.x;
    if (i >= n4) return;
    float4 v = ((const float4*)src)[i];
    ushort4 o;
    o.x = f_to_bf16(v.x); o.y = f_to_bf16(v.y);
    o.z = f_to_bf16(v.z); o.w = f_to_bf16(v.w);
    ((ushort4*)dst)[i] = o;
}

// ---- position map, query-major: pm2[h][i][j] = pos_map[i,j,h]*SCALE ----
__global__ void pos_kernel(const float* __restrict__ w1,   // (768,2)
                           const float* __restrict__ w1b,  // (768,)
                           const float* __restrict__ w2,   // (768,)
                           const float* __restrict__ b2,   // (12,)
                           float* __restrict__ pm2) {
    int idx = blockIdx.x * 256 + threadIdx.x;
    if (idx >= NHEAD * NTOK * NTOK) return;
    int h = idx / PM_H;
    int r = idx - h * PM_H;
    int i = r / NTOK;      // query row (slow)
    int j = r - i * NTOK;  // key col (fast)
    float rx = (float)(j % 14 - i % 14);   // indx[i][j]
    float ry = (float)(j / 14 - i / 14);   // indy[i][j]
    float acc = 0.f;
    int base = h * HDIM;
    #pragma unroll 8
    for (int t = 0; t < HDIM; ++t) {
        int c = base + t;
        float e = rx * w1[2 * c] + ry * w1[2 * c + 1] + w1b[c];
        e = e > 0.f ? e : 0.f;
        acc += e * w2[c];
    }
    pm2[idx] = (acc + b2[h]) * 0.125f;   // fold SCALE
}

// ---------------- GEMM1: qkv = x_bf @ w_cat^T (256x128 tile, dbuf K-loop)
// r10 diagnosis: with 128x128 blocks only 16 MFMAs (~160cy) sit between the
// two per-k-step barriers whose vmcnt(0) drain is ~500cy -> exposed stall;
// LDS reads 8 b128 per 16 MFMAs. This version: 256x128 block, wave tile
// 128x64 (acc[8][4]) -> 32 MFMAs/wave per barrier interval (2x amortization)
// and 12 b128 per 32 MFMAs (1.33x less LDS/FLOP); half the blocks.
// N-block width stays 128 -> all store mappings unchanged; m0 scales by 256
// (12544 = 49*256 exactly).
template <int MODE>
__global__ __launch_bounds__(256, 2) void gemm_qkv_t(
        const unsigned short* __restrict__ A,   // [12544][768] bf16
        const unsigned short* __restrict__ W,   // [2304][768] bf16
        unsigned short* __restrict__ qkv,
        int n0base) {
    __shared__ __align__(16) unsigned short As[2][256 * 32];
    __shared__ __align__(16) unsigned short Bs[2][128 * 32];
    int tid = threadIdx.x;
    int m0 = blockIdx.y * 256;
    int n0 = n0base + blockIdx.x * 128;
    int w = tid >> 6, lane = tid & 63, l15 = lane & 15, quad = lane >> 4;
    int mw = (w & 1) * 128, nw = (w >> 1) * 64;

    const unsigned short* ga = A + (size_t)(m0 + (tid >> 2)) * CDIM + (tid & 3) * 8;
    const unsigned short* gb = W + (size_t)(n0 + (tid >> 2)) * CDIM + (tid & 3) * 8;

    f32x4 acc[8][4];
    #pragma unroll
    for (int i = 0; i < 8; ++i)
        #pragma unroll
        for (int j = 0; j < 4; ++j) acc[i][j] = (f32x4){0.f, 0.f, 0.f, 0.f};

    auto issue = [&](int buf) {
        gld16(ga, &As[buf][tid * 8]);
        gld16(ga + 64 * CDIM, &As[buf][2048 + tid * 8]);
        gld16(ga + 128 * CDIM, &As[buf][4096 + tid * 8]);
        gld16(ga + 192 * CDIM, &As[buf][6144 + tid * 8]);
        gld16(gb, &Bs[buf][tid * 8]);
        gld16(gb + 64 * CDIM, &Bs[buf][2048 + tid * 8]);
        ga += 32; gb += 32;
    };
    auto compute = [&](int buf) {
        bf16x8 af[8], bf[4];
        #pragma unroll
        for (int mt = 0; mt < 8; ++mt)
            af[mt] = *(const bf16x8*)&As[buf][(mw + mt * 16 + l15) * 32 + quad * 8];
        #pragma unroll
        for (int nt = 0; nt < 4; ++nt)
            bf[nt] = *(const bf16x8*)&Bs[buf][(nw + nt * 16 + l15) * 32 + quad * 8];
        #pragma unroll
        for (int mt = 0; mt < 8; ++mt)
            #pragma unroll
            for (int nt = 0; nt < 4; ++nt) {
                if (MODE == 0)
                    acc[mt][nt] = __builtin_amdgcn_mfma_f32_16x16x32_bf16(bf[nt], af[mt], acc[mt][nt], 0, 0, 0);
                else
                    acc[mt][nt] = __builtin_amdgcn_mfma_f32_16x16x32_bf16(af[mt], bf[nt], acc[mt][nt], 0, 0, 0);
            }
    };

    issue(0);  // stage 0
    #pragma unroll 1
    for (int kt = 0; kt < 24; kt += 2) {
        __syncthreads();           // vmcnt drain -> buf0 stage visible
        issue(1);                  // stage kt+1 (kt+1 <= 23 always)
        compute(0);
        __syncthreads();
        if (kt + 2 < 24) issue(0); // stage kt+2
        compute(1);
    }

    if (MODE == 0) {
        // regs span c (d within head); lanes span token m
        int part = (n0 >= CDIM) ? 1 : 0;
        const size_t pbase = (size_t)part * PART_STRIDE;
        int cb = n0 + nw + quad * 4 - part * CDIM;     // 0..767, mult of 4
        #pragma unroll
        for (int mt = 0; mt < 8; ++mt) {
            int m = m0 + mw + mt * 16 + l15;
            int b = m / NTOK, n = m - b * NTOK;
            #pragma unroll
            for (int nt = 0; nt < 4; ++nt) {
                int c = cb + nt * 16;
                int h = c >> 6, d = c & 63;
                uint2 pv;
                pv.x = (unsigned int)f_to_bf16(acc[mt][nt][0]) |
                       ((unsigned int)f_to_bf16(acc[mt][nt][1]) << 16);
                pv.y = (unsigned int)f_to_bf16(acc[mt][nt][2]) |
                       ((unsigned int)f_to_bf16(acc[mt][nt][3]) << 16);
                size_t idx;
                if (part == 0)
                    idx = (size_t)(b * NHEAD + h) * BH_STRIDE + n * HDIM + d;
                else  // K2: [bh][kk][j][32]
                    idx = pbase + (size_t)(b * NHEAD + h) * BH_STRIDE +
                          (d >> 5) * K2G + n * 32 + (d & 31);
                *(uint2*)(qkv + idx) = pv;
            }
        }
    } else {
        // regs span token n (VT n-contiguous); lanes span c (d within head)
        #pragma unroll
        for (int mt = 0; mt < 8; ++mt) {
            int m = m0 + mw + mt * 16 + quad * 4;      // mult of 4; 4|196 so b,n uniform over r
            int b = m / NTOK, n = m - b * NTOK;
            size_t base_m = (size_t)2 * PART_STRIDE + (size_t)b * NHEAD * VT_BH + n;
            #pragma unroll
            for (int nt = 0; nt < 4; ++nt) {
                int c = n0 + nw + nt * 16 + l15 - 3 * 512;  // -1536
                int h = c >> 6, d = c & 63;
                uint2 pv;
                pv.x = (unsigned int)f_to_bf16(acc[mt][nt][0]) |
                       ((unsigned int)f_to_bf16(acc[mt][nt][1]) << 16);
                pv.y = (unsigned int)f_to_bf16(acc[mt][nt][2]) |
                       ((unsigned int)f_to_bf16(acc[mt][nt][3]) << 16);
                *(uint2*)(qkv + base_m + (size_t)h * VT_BH + d * VT_LD) = pv;
            }
        }
    }
}

// ---------------- MFMA attention v13 (r10, unchanged): 1 block = (b,h) ----
__global__ __launch_bounds__(256, 2) void attn_mfma(
        const unsigned short* __restrict__ qkv,
        const float* __restrict__ pm2,
        unsigned short* __restrict__ attn_out) {
    __shared__ __align__(16) unsigned short Ks[2 * K2G];         // 25,088 B swizzled
    __shared__ __align__(16) unsigned short Vs[64 * VT_LD];      // 28,672 B swizzled
    int bid = blockIdx.x;
    int m8 = (bid & 7) * 96 + (bid >> 3);   // XCD-chunked remap (768 = 8*96)
    int h = m8 >> 6, b = m8 & 63;           // head-major within chunk
    int bh = b * NHEAD + h;                 // memory layout unchanged
    int tid = threadIdx.x;
    int w = tid >> 6, lane = tid & 63;
    int l15 = lane & 15, quad = lane >> 4;

    const unsigned short* qbase = qkv + (size_t)bh * BH_STRIDE;
    const unsigned short* kbase = qkv + (size_t)PART_STRIDE + (size_t)bh * BH_STRIDE;
    const unsigned short* vbase = qkv + (size_t)2 * PART_STRIDE + (size_t)bh * VT_BH;
    const float* pmh = pm2 + (size_t)h * PM_H;

    // repack K2 global [kk][j][32] -> LDS [kk][j][32] with bits-4/5 XOR swizzle
    #pragma unroll
    for (int r = 0; r < 7; ++r) {
        int g = r * 2048 + tid * 8;
        if (g < 2 * K2G) {
            uint4 val = *(const uint4*)(kbase + g);
            int kk = (g >= K2G) ? 1 : 0;
            int rem = g - kk * K2G;
            int j = rem >> 5, c = rem & 31;
            *(uint4*)((char*)Ks + kk * K2HB + j * 64 + ((c * 2) ^ ((j & 3) << 4))) = val;
        }
    }
    // stage V^T global [d][224] -> LDS [d][224] with row&3 bits-4/5 XOR swizzle
    #pragma unroll
    for (int r = 0; r < 7; ++r) {
        int g = r * 4096 + tid * 16;                  // byte offset, 28,672 total
        uint4 val = *(const uint4*)((const char*)vbase + g);
        int d = g / 448, c = g - d * 448;
        *(uint4*)((char*)Vs + d * 448 + (c ^ ((d & 3) << 4))) = val;
    }
    __syncthreads();   // K + V staged

    // bpermute indices (byte addr = lane*4), constant per thread:
    // word u source lane = l15 + 16*(2*(q&1) + (u>>1))
    int q1 = (lane >> 4) & 1;
    int idx01 = (l15 + 32 * q1) * 4;      // u = 0,1
    int idx23 = idx01 + 64;               // u = 2,3
    bool lohalf = (lane < 32);            // q>>1 == 0 -> takes nt=2kk

    #pragma unroll 1
    for (int t = w; t < 13; t += 4) {
        // Q fragment (B-slot: lane l15 = i)
        int qrow = t * 16 + l15; if (qrow > 195) qrow = 195;
        bf16x8 aq0 = *(const bf16x8*)(qbase + qrow * HDIM + quad * 8);
        bf16x8 aq1 = *(const bf16x8*)(qbase + qrow * HDIM + 32 + quad * 8);

        const float* pmrow = pmh + qrow * NTOK;
        // pm ring prologue: nt = 0,1,2 in flight (jb <= 44, no clamp needed)
        float4 pmA = *(const float4*)(pmrow + quad * 4);
        float4 pmB = *(const float4*)(pmrow + 16 + quad * 4);
        float4 pmC = *(const float4*)(pmrow + 32 + quad * 4);

        float rsum = 0.f;
        unsigned int pk0[13], pk1[13];
        // fused QK-MFMA + softmax, pm ring lookahead 3
        #pragma unroll
        for (int nt = 0; nt < 13; ++nt) {
            int jc = nt * 16 + l15; if (jc > 195) jc = 195;
            const char* kb = (const char*)Ks + jc * 64 + ((quad * 16) ^ ((jc & 3) << 4));
            bf16x8 k0 = *(const bf16x8*)kb;
            bf16x8 k1 = *(const bf16x8*)(kb + K2HB);
            f32x4 s = (f32x4){0.f, 0.f, 0.f, 0.f};
            s = __builtin_amdgcn_mfma_f32_16x16x32_bf16(k0, aq0, s, 0, 0, 0);
            s = __builtin_amdgcn_mfma_f32_16x16x32_bf16(k1, aq1, s, 0, 0, 0);

            float4 pmv = (nt % 3 == 0) ? pmA : (nt % 3 == 1) ? pmB : pmC;
            if (nt + 3 < 13) {                       // refill ring slot with nt+3
                int jn = (nt + 3) * 16 + quad * 4; if (jn > 192) jn = 192;
                float4 nv = *(const float4*)(pmrow + jn);
                if (nt % 3 == 0) pmA = nv; else if (nt % 3 == 1) pmB = nv; else pmC = nv;
            }

            int jb = nt * 16 + quad * 4;
            float p0 = __expf(s[0] * pmv.x);
            float p1 = __expf(s[1] * pmv.y);
            float p2 = __expf(s[2] * pmv.z);
            float p3 = __expf(s[3] * pmv.w);
            if (jb + 0 > 195) p0 = 0.f;
            if (jb + 1 > 195) p1 = 0.f;
            if (jb + 2 > 195) p2 = 0.f;
            if (jb + 3 > 195) p3 = 0.f;
            rsum += (p0 + p1) + (p2 + p3);
            pk0[nt] = (unsigned int)f_to_bf16(p0) | ((unsigned int)f_to_bf16(p1) << 16);
            pk1[nt] = (unsigned int)f_to_bf16(p2) | ((unsigned int)f_to_bf16(p3) << 16);
        }
        rsum += __shfl_xor(rsum, 16);
        rsum += __shfl_xor(rsum, 32);
        float inv = 1.f / rsum;   // lane (q, l15) holds inv for row i = t*16+l15

        // O = mfma(P, V^T): A-fragment built by cross-lane shuffle, B from Vs
        f32x4 o[4];
        #pragma unroll
        for (int dt = 0; dt < 4; ++dt) o[dt] = (f32x4){0.f, 0.f, 0.f, 0.f};
        #pragma unroll
        for (int kk = 0; kk < 7; ++kk) {
            int a0 = (int)pk0[2 * kk],     a1 = (int)pk1[2 * kk];
            int b0 = (int)pk0[2 * kk + 1], b1 = (int)pk1[2 * kk + 1];
            int w0a = __builtin_amdgcn_ds_bpermute(idx01, a0);
            int w0b = __builtin_amdgcn_ds_bpermute(idx01, b0);
            int w1a = __builtin_amdgcn_ds_bpermute(idx01, a1);
            int w1b = __builtin_amdgcn_ds_bpermute(idx01, b1);
            int w2a = __builtin_amdgcn_ds_bpermute(idx23, a0);
            int w2b = __builtin_amdgcn_ds_bpermute(idx23, b0);
            int w3a = __builtin_amdgcn_ds_bpermute(idx23, a1);
            int w3b = __builtin_amdgcn_ds_bpermute(idx23, b1);
            union { uint4 u; bf16x8 v; } pw;
            pw.u.x = (unsigned int)(lohalf ? w0a : w0b);   // j = kk*32+q*8+0,1
            pw.u.y = (unsigned int)(lohalf ? w1a : w1b);   // +2,3
            pw.u.z = (unsigned int)(lohalf ? w2a : w2b);   // +4,5
            pw.u.w = (unsigned int)(lohalf ? w3a : w3b);   // +6,7
            bf16x8 pf = pw.v;
            #pragma unroll
            for (int dt = 0; dt < 4; ++dt) {
                bf16x8 vfr = *(const bf16x8*)((const char*)Vs + (dt * 16 + l15) * 448 +
                                              ((kk * 64 + quad * 16) ^ ((l15 & 3) << 4)));
                o[dt] = __builtin_amdgcn_mfma_f32_16x16x32_bf16(pf, vfr, o[dt], 0, 0, 0);
            }
        }

        // store: row i = t*16 + quad*4 + r, col d = dt*16 + l15
        #pragma unroll
        for (int r = 0; r < 4; ++r) {
            int row = t * 16 + quad * 4 + r;
            if (row < 196) {
                float iv = __shfl(inv, quad * 4 + r);   // from lane l15 = quad*4+r
                unsigned short* dst = attn_out + ((size_t)(b * NTOK + row)) * CDIM + h * HDIM + l15;
                #pragma unroll
                for (int dt = 0; dt < 4; ++dt)
                    dst[dt * 16] = f_to_bf16(o[dt][r] * iv);
            }
        }
    }
}

// ------ GEMM2: out = attn_o @ proj_w^T + proj_b (256x128 tile, float4 out)
__global__ __launch_bounds__(256, 2) void gemm_proj(
        const unsigned short* __restrict__ A,   // [12544][768] bf16
        const unsigned short* __restrict__ W,   // [768][768] bf16
        const float* __restrict__ bias,         // (768,)
        float* __restrict__ out) {
    __shared__ __align__(16) unsigned short As[2][256 * 32];
    __shared__ __align__(16) unsigned short Bs[2][128 * 32];
    int tid = threadIdx.x;
    int m0 = blockIdx.y * 256;
    int n0 = blockIdx.x * 128;
    int w = tid >> 6, lane = tid & 63, l15 = lane & 15, quad = lane >> 4;
    int mw = (w & 1) * 128, nw = (w >> 1) * 64;

    const unsigned short* ga = A + (size_t)(m0 + (tid >> 2)) * CDIM + (tid & 3) * 8;
    const unsigned short* gb = W + (size_t)(n0 + (tid >> 2)) * CDIM + (tid & 3) * 8;

    f32x4 acc[8][4];
    #pragma unroll
    for (int i = 0; i < 8; ++i)
        #pragma unroll
        for (int j = 0; j < 4; ++j) acc[i][j] = (f32x4){0.f, 0.f, 0.f, 0.f};

    auto issue = [&](int buf) {
        gld16(ga, &As[buf][tid * 8]);
        gld16(ga + 64 * CDIM, &As[buf][2048 + tid * 8]);
        gld16(ga + 128 * CDIM, &As[buf][4096 + tid * 8]);
        gld16(ga + 192 * CDIM, &As[buf][6144 + tid * 8]);
        gld16(gb, &Bs[buf][tid * 8]);
        gld16(gb + 64 * CDIM, &Bs[buf][2048 + tid * 8]);
        ga += 32; gb += 32;
    };
    auto compute = [&](int buf) {
        bf16x8 af[8], bf[4];
        #pragma unroll
        for (int mt = 0; mt < 8; ++mt)
            af[mt] = *(const bf16x8*)&As[buf][(mw + mt * 16 + l15) * 32 + quad * 8];
        #pragma unroll
        for (int nt = 0; nt < 4; ++nt)
            bf[nt] = *(const bf16x8*)&Bs[buf][(nw + nt * 16 + l15) * 32 + quad * 8];
        #pragma unroll
        for (int mt = 0; mt < 8; ++mt)
            #pragma unroll
            for (int nt = 0; nt < 4; ++nt)
                acc[mt][nt] = __builtin_amdgcn_mfma_f32_16x16x32_bf16(bf[nt], af[mt], acc[mt][nt], 0, 0, 0);
    };

    issue(0);
    #pragma unroll 1
    for (int kt = 0; kt < 24; kt += 2) {
        __syncthreads();
        issue(1);
        compute(0);
        __syncthreads();
        if (kt + 2 < 24) issue(0);
        compute(1);
    }

    // swapped: regs span out-col c (4 consec), lanes span out-row m
    #pragma unroll
    for (int nt = 0; nt < 4; ++nt) {
        int c = n0 + nw + nt * 16 + quad * 4;
        float4 bv = *(const float4*)(bias + c);
        #pragma unroll
        for (int mt = 0; mt < 8; ++mt) {
            int m = m0 + mw + mt * 16 + l15;
            float4 ov;
            ov.x = acc[mt][nt][0] + bv.x;
            ov.y = acc[mt][nt][1] + bv.y;
            ov.z = acc[mt][nt][2] + bv.z;
            ov.w = acc[mt][nt][3] + bv.w;
            *(float4*)(out + (size_t)m * CDIM + c) = ov;
        }
    }
}

extern "C" void kernel_launch(void* const* d_in, const int* in_sizes, int n_in,
                              void* d_out, int out_size, void* d_ws, size_t ws_size,
                              hipStream_t stream) {
    const float* x      = (const float*)d_in[0];
    const float* qk_w   = (const float*)d_in[1];
    const float* v_w    = (const float*)d_in[2];
    const float* w1_w   = (const float*)d_in[3];
    const float* w1_b   = (const float*)d_in[4];
    const float* w2     = (const float*)d_in[5];
    const float* b2     = (const float*)d_in[6];
    const float* proj_w = (const float*)d_in[7];
    const float* proj_b = (const float*)d_in[8];
    float* out = (float*)d_out;

    // workspace layout (bf16 = unsigned short)
    unsigned short* x_bf  = (unsigned short*)d_ws;            // 9,633,792 elems
    unsigned short* w_cat = x_bf + 9633792;                   // 1,769,472
    unsigned short* pw_bf = w_cat + 1769472;                  //   589,824
    float* pm2            = (float*)(pw_bf + 589824);         //   460,992 f32
    unsigned short* qkv   = (unsigned short*)(pm2 + 460992);  // 30,277,632
    unsigned short* attn_o = x_bf;                            // alias (dead after gemm1)

    cvt_f32_bf16<<<9408, 256, 0, stream>>>(x, x_bf, 2408448);
    cvt_f32_bf16<<<1152, 256, 0, stream>>>(qk_w, w_cat, 294912);
    cvt_f32_bf16<<<576, 256, 0, stream>>>(v_w, w_cat + 1179648, 147456);
    cvt_f32_bf16<<<576, 256, 0, stream>>>(proj_w, pw_bf, 147456);
    pos_kernel<<<1801, 256, 0, stream>>>(w1_w, w1_b, w2, b2, pm2);

    dim3 gqk(12, 49);
    gemm_qkv_t<0><<<gqk, 256, 0, stream>>>(x_bf, w_cat, qkv, 0);
    dim3 gv(6, 49);
    gemm_qkv_t<1><<<gv, 256, 0, stream>>>(x_bf, w_cat, qkv, 1536);

    attn_mfma<<<768, 256, 0, stream>>>(qkv, pm2, attn_o);

    dim3 g2(6, 49);
    gemm_proj<<<g2, 256, 0, stream>>>(attn_o, pw_bf, proj_b, out);
}

// Round 13
// 268.347 us; speedup vs baseline: 1.1015x; 1.1015x over previous
//
#include <hip/hip_runtime.h>

#define NTOK 196
#define NHEAD 12
#define HDIM 64
#define CDIM 768
#define BSZ 64
#define MROWS (BSZ * NTOK)          // 12544
#define PART_STRIDE 9633792         // 64*12*196*64
#define BH_STRIDE 12544             // 196*64
#define VT_LD 224                   // padded key dim for V^T rows (7 k-steps of 32)
#define VT_BH (HDIM * VT_LD)        // 14336
#define PM_H (NTOK * NTOK)          // 38416
#define K2G 6272                    // 196*32: one kk half of K2 in GLOBAL
#define K2HB 12544                  // bytes per kk half in LDS (196*32*2, unpadded+swizzled)

typedef __bf16 bf16x8 __attribute__((ext_vector_type(8)));
typedef float f32x4 __attribute__((ext_vector_type(4)));

static __device__ __forceinline__ unsigned short f_to_bf16(float f) {
    union { float f; unsigned int i; } v; v.f = f;
    unsigned int x = v.i;
    unsigned int r = x + 0x7fffu + ((x >> 16) & 1u);  // RNE
    return (unsigned short)(r >> 16);
}

// async global->LDS, 16 B per lane. LDS dst must be wave-uniform base + lane*16.
static __device__ __forceinline__ void gld16(const unsigned short* g, unsigned short* l) {
    __builtin_amdgcn_global_load_lds(
        (__attribute__((address_space(1))) void*)(unsigned long long)(const void*)g,
        (__attribute__((address_space(3))) void*)(unsigned int)(unsigned long long)(void*)l,
        16, 0, 0);
}

static __device__ __forceinline__ void cvt_block(const float* __restrict__ src,
                                                 unsigned short* __restrict__ dst,
                                                 int b, int tid, int n4) {
    int i = b * 256 + tid;
    if (i >= n4) return;
    float4 v = ((const float4*)src)[i];
    ushort4 o;
    o.x = f_to_bf16(v.x); o.y = f_to_bf16(v.y);
    o.z = f_to_bf16(v.z); o.w = f_to_bf16(v.w);
    ((ushort4*)dst)[i] = o;
}

// ---------- merged preprocessing: pos (first, longest pole) + 4 casts ------
// r11 accounting: 9 dependent dispatches cost ~launch gaps + per-kernel
// ramp/tail. All 5 preprocessing kernels are independent -> one dispatch.
__global__ __launch_bounds__(256) void prep_all(
        const float* __restrict__ x,      const float* __restrict__ qk_w,
        const float* __restrict__ v_w,    const float* __restrict__ proj_w,
        const float* __restrict__ w1,     const float* __restrict__ w1b,
        const float* __restrict__ w2,     const float* __restrict__ b2,
        unsigned short* __restrict__ x_bf, unsigned short* __restrict__ w_cat,
        unsigned short* __restrict__ pw_bf, float* __restrict__ pm2) {
    int bid = blockIdx.x;
    int tid = threadIdx.x;
    if (bid < 1801) {                       // pos map
        int idx = bid * 256 + tid;
        if (idx >= NHEAD * NTOK * NTOK) return;
        int h = idx / PM_H;
        int r = idx - h * PM_H;
        int i = r / NTOK;
        int j = r - i * NTOK;
        float rx = (float)(j % 14 - i % 14);
        float ry = (float)(j / 14 - i / 14);
        float acc = 0.f;
        int base = h * HDIM;
        #pragma unroll 8
        for (int t = 0; t < HDIM; ++t) {
            int c = base + t;
            float e = rx * w1[2 * c] + ry * w1[2 * c + 1] + w1b[c];
            e = e > 0.f ? e : 0.f;
            acc += e * w2[c];
        }
        pm2[idx] = (acc + b2[h]) * 0.125f;  // fold SCALE
    } else if (bid < 11209) {               // x cast (9408 blocks)
        cvt_block(x, x_bf, bid - 1801, tid, 2408448);
    } else if (bid < 12361) {               // qk_w cast (1152)
        cvt_block(qk_w, w_cat, bid - 11209, tid, 294912);
    } else if (bid < 12937) {               // v_w cast (576)
        cvt_block(v_w, w_cat + 1179648, bid - 12361, tid, 147456);
    } else {                                // proj_w cast (576)
        cvt_block(proj_w, pw_bf, bid - 12937, tid, 147456);
    }
}

// ---------------- GEMM1 body (r10 128x128 tile, dbuf K-loop) --------------
// MODE 0 (cols 0..1535): swapped mfma(B,A) -> regs span d. Q / K2 stores.
// MODE 1 (cols 1536..2303): normal mfma -> regs span n -> VT stores.
template <int MODE>
static __device__ __forceinline__ void qkv_body(
        const unsigned short* __restrict__ A,
        const unsigned short* __restrict__ W,
        unsigned short* __restrict__ qkv,
        int m0, int n0, int tid,
        unsigned short (&As)[2][128 * 32], unsigned short (&Bs)[2][128 * 32]) {
    int w = tid >> 6, lane = tid & 63, l15 = lane & 15, quad = lane >> 4;
    int mw = (w & 1) * 64, nw = (w >> 1) * 64;

    const unsigned short* ga = A + (size_t)(m0 + (tid >> 2)) * CDIM + (tid & 3) * 8;
    const unsigned short* gb = W + (size_t)(n0 + (tid >> 2)) * CDIM + (tid & 3) * 8;

    f32x4 acc[4][4];
    #pragma unroll
    for (int i = 0; i < 4; ++i)
        #pragma unroll
        for (int j = 0; j < 4; ++j) acc[i][j] = (f32x4){0.f, 0.f, 0.f, 0.f};

    auto issue = [&](int buf) {
        gld16(ga, &As[buf][tid * 8]);
        gld16(ga + 64 * CDIM, &As[buf][2048 + tid * 8]);
        gld16(gb, &Bs[buf][tid * 8]);
        gld16(gb + 64 * CDIM, &Bs[buf][2048 + tid * 8]);
        ga += 32; gb += 32;
    };
    auto compute = [&](int buf) {
        bf16x8 af[4], bf[4];
        #pragma unroll
        for (int mt = 0; mt < 4; ++mt)
            af[mt] = *(const bf16x8*)&As[buf][(mw + mt * 16 + l15) * 32 + quad * 8];
        #pragma unroll
        for (int nt = 0; nt < 4; ++nt)
            bf[nt] = *(const bf16x8*)&Bs[buf][(nw + nt * 16 + l15) * 32 + quad * 8];
        #pragma unroll
        for (int mt = 0; mt < 4; ++mt)
            #pragma unroll
            for (int nt = 0; nt < 4; ++nt) {
                if (MODE == 0)
                    acc[mt][nt] = __builtin_amdgcn_mfma_f32_16x16x32_bf16(bf[nt], af[mt], acc[mt][nt], 0, 0, 0);
                else
                    acc[mt][nt] = __builtin_amdgcn_mfma_f32_16x16x32_bf16(af[mt], bf[nt], acc[mt][nt], 0, 0, 0);
            }
    };

    issue(0);  // stage 0
    #pragma unroll 1
    for (int kt = 0; kt < 24; kt += 2) {
        __syncthreads();           // vmcnt drain -> buf0 stage visible
        issue(1);                  // stage kt+1
        compute(0);
        __syncthreads();
        if (kt + 2 < 24) issue(0); // stage kt+2
        compute(1);
    }

    if (MODE == 0) {
        int part = (n0 >= CDIM) ? 1 : 0;
        const size_t pbase = (size_t)part * PART_STRIDE;
        int cb = n0 + nw + quad * 4 - part * CDIM;     // 0..767, mult of 4
        #pragma unroll
        for (int mt = 0; mt < 4; ++mt) {
            int m = m0 + mw + mt * 16 + l15;
            int b = m / NTOK, n = m - b * NTOK;
            #pragma unroll
            for (int nt = 0; nt < 4; ++nt) {
                int c = cb + nt * 16;
                int h = c >> 6, d = c & 63;
                uint2 pv;
                pv.x = (unsigned int)f_to_bf16(acc[mt][nt][0]) |
                       ((unsigned int)f_to_bf16(acc[mt][nt][1]) << 16);
                pv.y = (unsigned int)f_to_bf16(acc[mt][nt][2]) |
                       ((unsigned int)f_to_bf16(acc[mt][nt][3]) << 16);
                size_t idx;
                if (part == 0)
                    idx = (size_t)(b * NHEAD + h) * BH_STRIDE + n * HDIM + d;
                else  // K2: [bh][kk][j][32]
                    idx = pbase + (size_t)(b * NHEAD + h) * BH_STRIDE +
                          (d >> 5) * K2G + n * 32 + (d & 31);
                *(uint2*)(qkv + idx) = pv;
            }
        }
    } else {
        #pragma unroll
        for (int mt = 0; mt < 4; ++mt) {
            int m = m0 + mw + mt * 16 + quad * 4;      // 4|196 so b,n uniform over r
            int b = m / NTOK, n = m - b * NTOK;
            size_t base_m = (size_t)2 * PART_STRIDE + (size_t)b * NHEAD * VT_BH + n;
            #pragma unroll
            for (int nt = 0; nt < 4; ++nt) {
                int c = n0 + nw + nt * 16 + l15 - 3 * 512;  // -1536
                int h = c >> 6, d = c & 63;
                uint2 pv;
                pv.x = (unsigned int)f_to_bf16(acc[mt][nt][0]) |
                       ((unsigned int)f_to_bf16(acc[mt][nt][1]) << 16);
                pv.y = (unsigned int)f_to_bf16(acc[mt][nt][2]) |
                       ((unsigned int)f_to_bf16(acc[mt][nt][3]) << 16);
                *(uint2*)(qkv + base_m + (size_t)h * VT_BH + d * VT_LD) = pv;
            }
        }
    }
}

// merged qkv GEMM: grid (18, 98); bx<12 -> mode0 (Q,K2), bx>=12 -> mode1 (VT).
// Both modes share A rows per blockIdx.y -> L2 locality preserved; mode-1
// blocks fill mode-0's dispatch tail (one launch gap + tail round removed).
// The mode branch is on blockIdx.x -> block-uniform -> __syncthreads inside
// qkv_body is safe.
__global__ __launch_bounds__(256) void gemm_qkv_all(
        const unsigned short* __restrict__ A,
        const unsigned short* __restrict__ W,
        unsigned short* __restrict__ qkv) {
    __shared__ __align__(16) unsigned short As[2][128 * 32];
    __shared__ __align__(16) unsigned short Bs[2][128 * 32];
    int bx = blockIdx.x;
    int m0 = blockIdx.y * 128;
    if (bx < 12)
        qkv_body<0>(A, W, qkv, m0, bx * 128, threadIdx.x, As, Bs);
    else
        qkv_body<1>(A, W, qkv, m0, 1536 + (bx - 12) * 128, threadIdx.x, As, Bs);
}

// ---------------- MFMA attention v13 (r10, unchanged): 1 block = (b,h) ----
__global__ __launch_bounds__(256, 2) void attn_mfma(
        const unsigned short* __restrict__ qkv,
        const float* __restrict__ pm2,
        unsigned short* __restrict__ attn_out) {
    __shared__ __align__(16) unsigned short Ks[2 * K2G];         // 25,088 B swizzled
    __shared__ __align__(16) unsigned short Vs[64 * VT_LD];      // 28,672 B swizzled
    int bid = blockIdx.x;
    int m8 = (bid & 7) * 96 + (bid >> 3);   // XCD-chunked remap (768 = 8*96)
    int h = m8 >> 6, b = m8 & 63;           // head-major within chunk
    int bh = b * NHEAD + h;                 // memory layout unchanged
    int tid = threadIdx.x;
    int w = tid >> 6, lane = tid & 63;
    int l15 = lane & 15, quad = lane >> 4;

    const unsigned short* qbase = qkv + (size_t)bh * BH_STRIDE;
    const unsigned short* kbase = qkv + (size_t)PART_STRIDE + (size_t)bh * BH_STRIDE;
    const unsigned short* vbase = qkv + (size_t)2 * PART_STRIDE + (size_t)bh * VT_BH;
    const float* pmh = pm2 + (size_t)h * PM_H;

    // repack K2 global [kk][j][32] -> LDS [kk][j][32] with bits-4/5 XOR swizzle
    #pragma unroll
    for (int r = 0; r < 7; ++r) {
        int g = r * 2048 + tid * 8;
        if (g < 2 * K2G) {
            uint4 val = *(const uint4*)(kbase + g);
            int kk = (g >= K2G) ? 1 : 0;
            int rem = g - kk * K2G;
            int j = rem >> 5, c = rem & 31;
            *(uint4*)((char*)Ks + kk * K2HB + j * 64 + ((c * 2) ^ ((j & 3) << 4))) = val;
        }
    }
    // stage V^T global [d][224] -> LDS [d][224] with row&3 bits-4/5 XOR swizzle
    #pragma unroll
    for (int r = 0; r < 7; ++r) {
        int g = r * 4096 + tid * 16;                  // byte offset, 28,672 total
        uint4 val = *(const uint4*)((const char*)vbase + g);
        int d = g / 448, c = g - d * 448;
        *(uint4*)((char*)Vs + d * 448 + (c ^ ((d & 3) << 4))) = val;
    }
    __syncthreads();   // K + V staged

    // bpermute indices (byte addr = lane*4), constant per thread:
    // word u source lane = l15 + 16*(2*(q&1) + (u>>1))
    int q1 = (lane >> 4) & 1;
    int idx01 = (l15 + 32 * q1) * 4;      // u = 0,1
    int idx23 = idx01 + 64;               // u = 2,3
    bool lohalf = (lane < 32);            // q>>1 == 0 -> takes nt=2kk

    #pragma unroll 1
    for (int t = w; t < 13; t += 4) {
        // Q fragment (B-slot: lane l15 = i)
        int qrow = t * 16 + l15; if (qrow > 195) qrow = 195;
        bf16x8 aq0 = *(const bf16x8*)(qbase + qrow * HDIM + quad * 8);
        bf16x8 aq1 = *(const bf16x8*)(qbase + qrow * HDIM + 32 + quad * 8);

        const float* pmrow = pmh + qrow * NTOK;
        // pm ring prologue: nt = 0,1,2 in flight (jb <= 44, no clamp needed)
        float4 pmA = *(const float4*)(pmrow + quad * 4);
        float4 pmB = *(const float4*)(pmrow + 16 + quad * 4);
        float4 pmC = *(const float4*)(pmrow + 32 + quad * 4);

        float rsum = 0.f;
        unsigned int pk0[13], pk1[13];
        // fused QK-MFMA + softmax, pm ring lookahead 3
        #pragma unroll
        for (int nt = 0; nt < 13; ++nt) {
            int jc = nt * 16 + l15; if (jc > 195) jc = 195;
            const char* kb = (const char*)Ks + jc * 64 + ((quad * 16) ^ ((jc & 3) << 4));
            bf16x8 k0 = *(const bf16x8*)kb;
            bf16x8 k1 = *(const bf16x8*)(kb + K2HB);
            f32x4 s = (f32x4){0.f, 0.f, 0.f, 0.f};
            s = __builtin_amdgcn_mfma_f32_16x16x32_bf16(k0, aq0, s, 0, 0, 0);
            s = __builtin_amdgcn_mfma_f32_16x16x32_bf16(k1, aq1, s, 0, 0, 0);

            float4 pmv = (nt % 3 == 0) ? pmA : (nt % 3 == 1) ? pmB : pmC;
            if (nt + 3 < 13) {                       // refill ring slot with nt+3
                int jn = (nt + 3) * 16 + quad * 4; if (jn > 192) jn = 192;
                float4 nv = *(const float4*)(pmrow + jn);
                if (nt % 3 == 0) pmA = nv; else if (nt % 3 == 1) pmB = nv; else pmC = nv;
            }

            int jb = nt * 16 + quad * 4;
            float p0 = __expf(s[0] * pmv.x);
            float p1 = __expf(s[1] * pmv.y);
            float p2 = __expf(s[2] * pmv.z);
            float p3 = __expf(s[3] * pmv.w);
            if (jb + 0 > 195) p0 = 0.f;
            if (jb + 1 > 195) p1 = 0.f;
            if (jb + 2 > 195) p2 = 0.f;
            if (jb + 3 > 195) p3 = 0.f;
            rsum += (p0 + p1) + (p2 + p3);
            pk0[nt] = (unsigned int)f_to_bf16(p0) | ((unsigned int)f_to_bf16(p1) << 16);
            pk1[nt] = (unsigned int)f_to_bf16(p2) | ((unsigned int)f_to_bf16(p3) << 16);
        }
        rsum += __shfl_xor(rsum, 16);
        rsum += __shfl_xor(rsum, 32);
        float inv = 1.f / rsum;   // lane (q, l15) holds inv for row i = t*16+l15

        // O = mfma(P, V^T): A-fragment built by cross-lane shuffle, B from Vs
        f32x4 o[4];
        #pragma unroll
        for (int dt = 0; dt < 4; ++dt) o[dt] = (f32x4){0.f, 0.f, 0.f, 0.f};
        #pragma unroll
        for (int kk = 0; kk < 7; ++kk) {
            int a0 = (int)pk0[2 * kk],     a1 = (int)pk1[2 * kk];
            int b0 = (int)pk0[2 * kk + 1], b1 = (int)pk1[2 * kk + 1];
            int w0a = __builtin_amdgcn_ds_bpermute(idx01, a0);
            int w0b = __builtin_amdgcn_ds_bpermute(idx01, b0);
            int w1a = __builtin_amdgcn_ds_bpermute(idx01, a1);
            int w1b = __builtin_amdgcn_ds_bpermute(idx01, b1);
            int w2a = __builtin_amdgcn_ds_bpermute(idx23, a0);
            int w2b = __builtin_amdgcn_ds_bpermute(idx23, b0);
            int w3a = __builtin_amdgcn_ds_bpermute(idx23, a1);
            int w3b = __builtin_amdgcn_ds_bpermute(idx23, b1);
            union { uint4 u; bf16x8 v; } pw;
            pw.u.x = (unsigned int)(lohalf ? w0a : w0b);   // j = kk*32+q*8+0,1
            pw.u.y = (unsigned int)(lohalf ? w1a : w1b);   // +2,3
            pw.u.z = (unsigned int)(lohalf ? w2a : w2b);   // +4,5
            pw.u.w = (unsigned int)(lohalf ? w3a : w3b);   // +6,7
            bf16x8 pf = pw.v;
            #pragma unroll
            for (int dt = 0; dt < 4; ++dt) {
                bf16x8 vfr = *(const bf16x8*)((const char*)Vs + (dt * 16 + l15) * 448 +
                                              ((kk * 64 + quad * 16) ^ ((l15 & 3) << 4)));
                o[dt] = __builtin_amdgcn_mfma_f32_16x16x32_bf16(pf, vfr, o[dt], 0, 0, 0);
            }
        }

        // store: row i = t*16 + quad*4 + r, col d = dt*16 + l15
        #pragma unroll
        for (int r = 0; r < 4; ++r) {
            int row = t * 16 + quad * 4 + r;
            if (row < 196) {
                float iv = __shfl(inv, quad * 4 + r);   // from lane l15 = quad*4+r
                unsigned short* dst = attn_out + ((size_t)(b * NTOK + row)) * CDIM + h * HDIM + l15;
                #pragma unroll
                for (int dt = 0; dt < 4; ++dt)
                    dst[dt * 16] = f_to_bf16(o[dt][r] * iv);
            }
        }
    }
}

// ------ GEMM2 (r10, 128x128): out = attn_o @ proj_w^T + proj_b ------------
__global__ __launch_bounds__(256) void gemm_proj(
        const unsigned short* __restrict__ A,   // [12544][768] bf16
        const unsigned short* __restrict__ W,   // [768][768] bf16
        const float* __restrict__ bias,         // (768,)
        float* __restrict__ out) {
    __shared__ __align__(16) unsigned short As[2][128 * 32];
    __shared__ __align__(16) unsigned short Bs[2][128 * 32];
    int tid = threadIdx.x;
    int m0 = blockIdx.y * 128;
    int n0 = blockIdx.x * 128;
    int w = tid >> 6, lane = tid & 63, l15 = lane & 15, quad = lane >> 4;
    int mw = (w & 1) * 64, nw = (w >> 1) * 64;

    const unsigned short* ga = A + (size_t)(m0 + (tid >> 2)) * CDIM + (tid & 3) * 8;
    const unsigned short* gb = W + (size_t)(n0 + (tid >> 2)) * CDIM + (tid & 3) * 8;

    f32x4 acc[4][4];
    #pragma unroll
    for (int i = 0; i < 4; ++i)
        #pragma unroll
        for (int j = 0; j < 4; ++j) acc[i][j] = (f32x4){0.f, 0.f, 0.f, 0.f};

    auto issue = [&](int buf) {
        gld16(ga, &As[buf][tid * 8]);
        gld16(ga + 64 * CDIM, &As[buf][2048 + tid * 8]);
        gld16(gb, &Bs[buf][tid * 8]);
        gld16(gb + 64 * CDIM, &Bs[buf][2048 + tid * 8]);
        ga += 32; gb += 32;
    };
    auto compute = [&](int buf) {
        bf16x8 af[4], bf[4];
        #pragma unroll
        for (int mt = 0; mt < 4; ++mt)
            af[mt] = *(const bf16x8*)&As[buf][(mw + mt * 16 + l15) * 32 + quad * 8];
        #pragma unroll
        for (int nt = 0; nt < 4; ++nt)
            bf[nt] = *(const bf16x8*)&Bs[buf][(nw + nt * 16 + l15) * 32 + quad * 8];
        #pragma unroll
        for (int mt = 0; mt < 4; ++mt)
            #pragma unroll
            for (int nt = 0; nt < 4; ++nt)
                acc[mt][nt] = __builtin_amdgcn_mfma_f32_16x16x32_bf16(bf[nt], af[mt], acc[mt][nt], 0, 0, 0);
    };

    issue(0);
    #pragma unroll 1
    for (int kt = 0; kt < 24; kt += 2) {
        __syncthreads();
        issue(1);
        compute(0);
        __syncthreads();
        if (kt + 2 < 24) issue(0);
        compute(1);
    }

    // swapped: regs span out-col c (4 consec), lanes span out-row m
    #pragma unroll
    for (int nt = 0; nt < 4; ++nt) {
        int c = n0 + nw + nt * 16 + quad * 4;
        float4 bv = *(const float4*)(bias + c);
        #pragma unroll
        for (int mt = 0; mt < 4; ++mt) {
            int m = m0 + mw + mt * 16 + l15;
            float4 ov;
            ov.x = acc[mt][nt][0] + bv.x;
            ov.y = acc[mt][nt][1] + bv.y;
            ov.z = acc[mt][nt][2] + bv.z;
            ov.w = acc[mt][nt][3] + bv.w;
            *(float4*)(out + (size_t)m * CDIM + c) = ov;
        }
    }
}

extern "C" void kernel_launch(void* const* d_in, const int* in_sizes, int n_in,
                              void* d_out, int out_size, void* d_ws, size_t ws_size,
                              hipStream_t stream) {
    const float* x      = (const float*)d_in[0];
    const float* qk_w   = (const float*)d_in[1];
    const float* v_w    = (const float*)d_in[2];
    const float* w1_w   = (const float*)d_in[3];
    const float* w1_b   = (const float*)d_in[4];
    const float* w2     = (const float*)d_in[5];
    const float* b2     = (const float*)d_in[6];
    const float* proj_w = (const float*)d_in[7];
    const float* proj_b = (const float*)d_in[8];
    float* out = (float*)d_out;

    // workspace layout (bf16 = unsigned short)
    unsigned short* x_bf  = (unsigned short*)d_ws;            // 9,633,792 elems
    unsigned short* w_cat = x_bf + 9633792;                   // 1,769,472
    unsigned short* pw_bf = w_cat + 1769472;                  //   589,824
    float* pm2            = (float*)(pw_bf + 589824);         //   460,992 f32
    unsigned short* qkv   = (unsigned short*)(pm2 + 460992);  // 30,277,632
    unsigned short* attn_o = x_bf;                            // alias (dead after gemm1)

    // 4 dispatches total (was 9): prep_all -> gemm_qkv_all -> attn -> proj
    prep_all<<<13513, 256, 0, stream>>>(x, qk_w, v_w, proj_w,
                                        w1_w, w1_b, w2, b2,
                                        x_bf, w_cat, pw_bf, pm2);

    dim3 gqkv(18, 98);
    gemm_qkv_all<<<gqkv, 256, 0, stream>>>(x_bf, w_cat, qkv);

    attn_mfma<<<768, 256, 0, stream>>>(qkv, pm2, attn_o);

    dim3 g2(6, 98);
    gemm_proj<<<g2, 256, 0, stream>>>(attn_o, pw_bf, proj_b, out);
}

// Round 14
// 267.971 us; speedup vs baseline: 1.1031x; 1.0014x over previous
//
#include <hip/hip_runtime.h>

#define NTOK 196
#define NHEAD 12
#define HDIM 64
#define CDIM 768
#define BSZ 64
#define MROWS (BSZ * NTOK)          // 12544
#define PART_STRIDE 9633792         // 64*12*196*64
#define BH_STRIDE 12544             // 196*64
#define VT_LD 224                   // padded key dim for V^T rows (7 k-steps of 32)
#define VT_BH (HDIM * VT_LD)        // 14336
#define PM_H (NTOK * NTOK)          // 38416
#define K2G 6272                    // 196*32: one kk half of K2 in GLOBAL
#define K2HB 12544                  // bytes per kk half in LDS (196*32*2, unpadded+swizzled)

typedef __bf16 bf16x8 __attribute__((ext_vector_type(8)));
typedef float f32x4 __attribute__((ext_vector_type(4)));

static __device__ __forceinline__ unsigned short f_to_bf16(float f) {
    union { float f; unsigned int i; } v; v.f = f;
    unsigned int x = v.i;
    unsigned int r = x + 0x7fffu + ((x >> 16) & 1u);  // RNE
    return (unsigned short)(r >> 16);
}

// async global->LDS, 16 B per lane. LDS dst must be wave-uniform base + lane*16.
static __device__ __forceinline__ void gld16(const unsigned short* g, unsigned short* l) {
    __builtin_amdgcn_global_load_lds(
        (__attribute__((address_space(1))) void*)(unsigned long long)(const void*)g,
        (__attribute__((address_space(3))) void*)(unsigned int)(unsigned long long)(void*)l,
        16, 0, 0);
}

static __device__ __forceinline__ void cvt_block(const float* __restrict__ src,
                                                 unsigned short* __restrict__ dst,
                                                 int b, int tid, int n4) {
    int i = b * 256 + tid;
    if (i >= n4) return;
    float4 v = ((const float4*)src)[i];
    ushort4 o;
    o.x = f_to_bf16(v.x); o.y = f_to_bf16(v.y);
    o.z = f_to_bf16(v.z); o.w = f_to_bf16(v.w);
    ((ushort4*)dst)[i] = o;
}

// ---------- merged preprocessing: pos (first, longest pole) + 4 casts ------
__global__ __launch_bounds__(256) void prep_all(
        const float* __restrict__ x,      const float* __restrict__ qk_w,
        const float* __restrict__ v_w,    const float* __restrict__ proj_w,
        const float* __restrict__ w1,     const float* __restrict__ w1b,
        const float* __restrict__ w2,     const float* __restrict__ b2,
        unsigned short* __restrict__ x_bf, unsigned short* __restrict__ w_cat,
        unsigned short* __restrict__ pw_bf, float* __restrict__ pm2) {
    int bid = blockIdx.x;
    int tid = threadIdx.x;
    if (bid < 1801) {                       // pos map
        int idx = bid * 256 + tid;
        if (idx >= NHEAD * NTOK * NTOK) return;
        int h = idx / PM_H;
        int r = idx - h * PM_H;
        int i = r / NTOK;
        int j = r - i * NTOK;
        float rx = (float)(j % 14 - i % 14);
        float ry = (float)(j / 14 - i / 14);
        float acc = 0.f;
        int base = h * HDIM;
        #pragma unroll 8
        for (int t = 0; t < HDIM; ++t) {
            int c = base + t;
            float e = rx * w1[2 * c] + ry * w1[2 * c + 1] + w1b[c];
            e = e > 0.f ? e : 0.f;
            acc += e * w2[c];
        }
        pm2[idx] = (acc + b2[h]) * 0.125f;  // fold SCALE
    } else if (bid < 11209) {               // x cast (9408 blocks)
        cvt_block(x, x_bf, bid - 1801, tid, 2408448);
    } else if (bid < 12361) {               // qk_w cast (1152)
        cvt_block(qk_w, w_cat, bid - 11209, tid, 294912);
    } else if (bid < 12937) {               // v_w cast (576)
        cvt_block(v_w, w_cat + 1179648, bid - 12361, tid, 147456);
    } else {                                // proj_w cast (576)
        cvt_block(proj_w, pw_bf, bid - 12937, tid, 147456);
    }
}

// ---------------- GEMM1 body (r10 128x128 tile, dbuf K-loop) --------------
// MODE 0 (cols 0..1535): swapped mfma(B,A) -> regs span d. Q / K2 stores.
// MODE 1 (cols 1536..2303): normal mfma -> regs span n -> VT stores.
template <int MODE>
static __device__ __forceinline__ void qkv_body(
        const unsigned short* __restrict__ A,
        const unsigned short* __restrict__ W,
        unsigned short* __restrict__ qkv,
        int m0, int n0, int tid,
        unsigned short (&As)[2][128 * 32], unsigned short (&Bs)[2][128 * 32]) {
    int w = tid >> 6, lane = tid & 63, l15 = lane & 15, quad = lane >> 4;
    int mw = (w & 1) * 64, nw = (w >> 1) * 64;

    const unsigned short* ga = A + (size_t)(m0 + (tid >> 2)) * CDIM + (tid & 3) * 8;
    const unsigned short* gb = W + (size_t)(n0 + (tid >> 2)) * CDIM + (tid & 3) * 8;

    f32x4 acc[4][4];
    #pragma unroll
    for (int i = 0; i < 4; ++i)
        #pragma unroll
        for (int j = 0; j < 4; ++j) acc[i][j] = (f32x4){0.f, 0.f, 0.f, 0.f};

    auto issue = [&](int buf) {
        gld16(ga, &As[buf][tid * 8]);
        gld16(ga + 64 * CDIM, &As[buf][2048 + tid * 8]);
        gld16(gb, &Bs[buf][tid * 8]);
        gld16(gb + 64 * CDIM, &Bs[buf][2048 + tid * 8]);
        ga += 32; gb += 32;
    };
    auto compute = [&](int buf) {
        bf16x8 af[4], bf[4];
        #pragma unroll
        for (int mt = 0; mt < 4; ++mt)
            af[mt] = *(const bf16x8*)&As[buf][(mw + mt * 16 + l15) * 32 + quad * 8];
        #pragma unroll
        for (int nt = 0; nt < 4; ++nt)
            bf[nt] = *(const bf16x8*)&Bs[buf][(nw + nt * 16 + l15) * 32 + quad * 8];
        #pragma unroll
        for (int mt = 0; mt < 4; ++mt)
            #pragma unroll
            for (int nt = 0; nt < 4; ++nt) {
                if (MODE == 0)
                    acc[mt][nt] = __builtin_amdgcn_mfma_f32_16x16x32_bf16(bf[nt], af[mt], acc[mt][nt], 0, 0, 0);
                else
                    acc[mt][nt] = __builtin_amdgcn_mfma_f32_16x16x32_bf16(af[mt], bf[nt], acc[mt][nt], 0, 0, 0);
            }
    };

    issue(0);  // stage 0
    #pragma unroll 1
    for (int kt = 0; kt < 24; kt += 2) {
        __syncthreads();           // vmcnt drain -> buf0 stage visible
        issue(1);                  // stage kt+1
        compute(0);
        __syncthreads();
        if (kt + 2 < 24) issue(0); // stage kt+2
        compute(1);
    }

    if (MODE == 0) {
        int part = (n0 >= CDIM) ? 1 : 0;
        const size_t pbase = (size_t)part * PART_STRIDE;
        int cb = n0 + nw + quad * 4 - part * CDIM;     // 0..767, mult of 4
        #pragma unroll
        for (int mt = 0; mt < 4; ++mt) {
            int m = m0 + mw + mt * 16 + l15;
            int b = m / NTOK, n = m - b * NTOK;
            #pragma unroll
            for (int nt = 0; nt < 4; ++nt) {
                int c = cb + nt * 16;
                int h = c >> 6, d = c & 63;
                uint2 pv;
                pv.x = (unsigned int)f_to_bf16(acc[mt][nt][0]) |
                       ((unsigned int)f_to_bf16(acc[mt][nt][1]) << 16);
                pv.y = (unsigned int)f_to_bf16(acc[mt][nt][2]) |
                       ((unsigned int)f_to_bf16(acc[mt][nt][3]) << 16);
                size_t idx;
                if (part == 0)
                    idx = (size_t)(b * NHEAD + h) * BH_STRIDE + n * HDIM + d;
                else  // K2: [bh][kk][j][32]
                    idx = pbase + (size_t)(b * NHEAD + h) * BH_STRIDE +
                          (d >> 5) * K2G + n * 32 + (d & 31);
                *(uint2*)(qkv + idx) = pv;
            }
        }
    } else {
        #pragma unroll
        for (int mt = 0; mt < 4; ++mt) {
            int m = m0 + mw + mt * 16 + quad * 4;      // 4|196 so b,n uniform over r
            int b = m / NTOK, n = m - b * NTOK;
            size_t base_m = (size_t)2 * PART_STRIDE + (size_t)b * NHEAD * VT_BH + n;
            #pragma unroll
            for (int nt = 0; nt < 4; ++nt) {
                int c = n0 + nw + nt * 16 + l15 - 3 * 512;  // -1536
                int h = c >> 6, d = c & 63;
                uint2 pv;
                pv.x = (unsigned int)f_to_bf16(acc[mt][nt][0]) |
                       ((unsigned int)f_to_bf16(acc[mt][nt][1]) << 16);
                pv.y = (unsigned int)f_to_bf16(acc[mt][nt][2]) |
                       ((unsigned int)f_to_bf16(acc[mt][nt][3]) << 16);
                *(uint2*)(qkv + base_m + (size_t)h * VT_BH + d * VT_LD) = pv;
            }
        }
    }
}

// merged qkv GEMM: 1764 blocks, XCD-chunked bijective remap (1764 = 8*220+4).
// r13 diagnosis: FETCH 104.5 MB vs ~23 MB compulsory -> A-panels (shared by
// the 18 same-row blocks) pulled into many per-XCD L2s; barrier drains then
// wait on HBM-latency (~900cy) staging instead of L2 (~200cy). Remap gives
// XCD x a contiguous row-major chunk (~12 rows x 18 cols): per-XCD working
// set A ~2.4 MB + W 3.4 MB ~= L2 -> staging loads become L2 hits.
// Mode branch stays block-uniform -> __syncthreads in qkv_body safe.
__global__ __launch_bounds__(256) void gemm_qkv_all(
        const unsigned short* __restrict__ A,
        const unsigned short* __restrict__ W,
        unsigned short* __restrict__ qkv) {
    __shared__ __align__(16) unsigned short As[2][128 * 32];
    __shared__ __align__(16) unsigned short Bs[2][128 * 32];
    int l = blockIdx.y * 18 + blockIdx.x;
    int xcd = l & 7, idx = l >> 3;
    int t = (xcd < 4) ? xcd * 221 + idx : 884 + (xcd - 4) * 220 + idx;  // bijective
    int by = t / 18, bx = t - by * 18;
    int m0 = by * 128;
    if (bx < 12)
        qkv_body<0>(A, W, qkv, m0, bx * 128, threadIdx.x, As, Bs);
    else
        qkv_body<1>(A, W, qkv, m0, 1536 + (bx - 12) * 128, threadIdx.x, As, Bs);
}

// ---------------- MFMA attention v13 (r10, unchanged): 1 block = (b,h) ----
__global__ __launch_bounds__(256, 2) void attn_mfma(
        const unsigned short* __restrict__ qkv,
        const float* __restrict__ pm2,
        unsigned short* __restrict__ attn_out) {
    __shared__ __align__(16) unsigned short Ks[2 * K2G];         // 25,088 B swizzled
    __shared__ __align__(16) unsigned short Vs[64 * VT_LD];      // 28,672 B swizzled
    int bid = blockIdx.x;
    int m8 = (bid & 7) * 96 + (bid >> 3);   // XCD-chunked remap (768 = 8*96)
    int h = m8 >> 6, b = m8 & 63;           // head-major within chunk
    int bh = b * NHEAD + h;                 // memory layout unchanged
    int tid = threadIdx.x;
    int w = tid >> 6, lane = tid & 63;
    int l15 = lane & 15, quad = lane >> 4;

    const unsigned short* qbase = qkv + (size_t)bh * BH_STRIDE;
    const unsigned short* kbase = qkv + (size_t)PART_STRIDE + (size_t)bh * BH_STRIDE;
    const unsigned short* vbase = qkv + (size_t)2 * PART_STRIDE + (size_t)bh * VT_BH;
    const float* pmh = pm2 + (size_t)h * PM_H;

    // repack K2 global [kk][j][32] -> LDS [kk][j][32] with bits-4/5 XOR swizzle
    #pragma unroll
    for (int r = 0; r < 7; ++r) {
        int g = r * 2048 + tid * 8;
        if (g < 2 * K2G) {
            uint4 val = *(const uint4*)(kbase + g);
            int kk = (g >= K2G) ? 1 : 0;
            int rem = g - kk * K2G;
            int j = rem >> 5, c = rem & 31;
            *(uint4*)((char*)Ks + kk * K2HB + j * 64 + ((c * 2) ^ ((j & 3) << 4))) = val;
        }
    }
    // stage V^T global [d][224] -> LDS [d][224] with row&3 bits-4/5 XOR swizzle
    #pragma unroll
    for (int r = 0; r < 7; ++r) {
        int g = r * 4096 + tid * 16;                  // byte offset, 28,672 total
        uint4 val = *(const uint4*)((const char*)vbase + g);
        int d = g / 448, c = g - d * 448;
        *(uint4*)((char*)Vs + d * 448 + (c ^ ((d & 3) << 4))) = val;
    }
    __syncthreads();   // K + V staged

    // bpermute indices (byte addr = lane*4), constant per thread:
    // word u source lane = l15 + 16*(2*(q&1) + (u>>1))
    int q1 = (lane >> 4) & 1;
    int idx01 = (l15 + 32 * q1) * 4;      // u = 0,1
    int idx23 = idx01 + 64;               // u = 2,3
    bool lohalf = (lane < 32);            // q>>1 == 0 -> takes nt=2kk

    #pragma unroll 1
    for (int t = w; t < 13; t += 4) {
        // Q fragment (B-slot: lane l15 = i)
        int qrow = t * 16 + l15; if (qrow > 195) qrow = 195;
        bf16x8 aq0 = *(const bf16x8*)(qbase + qrow * HDIM + quad * 8);
        bf16x8 aq1 = *(const bf16x8*)(qbase + qrow * HDIM + 32 + quad * 8);

        const float* pmrow = pmh + qrow * NTOK;
        // pm ring prologue: nt = 0,1,2 in flight (jb <= 44, no clamp needed)
        float4 pmA = *(const float4*)(pmrow + quad * 4);
        float4 pmB = *(const float4*)(pmrow + 16 + quad * 4);
        float4 pmC = *(const float4*)(pmrow + 32 + quad * 4);

        float rsum = 0.f;
        unsigned int pk0[13], pk1[13];
        // fused QK-MFMA + softmax, pm ring lookahead 3
        #pragma unroll
        for (int nt = 0; nt < 13; ++nt) {
            int jc = nt * 16 + l15; if (jc > 195) jc = 195;
            const char* kb = (const char*)Ks + jc * 64 + ((quad * 16) ^ ((jc & 3) << 4));
            bf16x8 k0 = *(const bf16x8*)kb;
            bf16x8 k1 = *(const bf16x8*)(kb + K2HB);
            f32x4 s = (f32x4){0.f, 0.f, 0.f, 0.f};
            s = __builtin_amdgcn_mfma_f32_16x16x32_bf16(k0, aq0, s, 0, 0, 0);
            s = __builtin_amdgcn_mfma_f32_16x16x32_bf16(k1, aq1, s, 0, 0, 0);

            float4 pmv = (nt % 3 == 0) ? pmA : (nt % 3 == 1) ? pmB : pmC;
            if (nt + 3 < 13) {                       // refill ring slot with nt+3
                int jn = (nt + 3) * 16 + quad * 4; if (jn > 192) jn = 192;
                float4 nv = *(const float4*)(pmrow + jn);
                if (nt % 3 == 0) pmA = nv; else if (nt % 3 == 1) pmB = nv; else pmC = nv;
            }

            int jb = nt * 16 + quad * 4;
            float p0 = __expf(s[0] * pmv.x);
            float p1 = __expf(s[1] * pmv.y);
            float p2 = __expf(s[2] * pmv.z);
            float p3 = __expf(s[3] * pmv.w);
            if (jb + 0 > 195) p0 = 0.f;
            if (jb + 1 > 195) p1 = 0.f;
            if (jb + 2 > 195) p2 = 0.f;
            if (jb + 3 > 195) p3 = 0.f;
            rsum += (p0 + p1) + (p2 + p3);
            pk0[nt] = (unsigned int)f_to_bf16(p0) | ((unsigned int)f_to_bf16(p1) << 16);
            pk1[nt] = (unsigned int)f_to_bf16(p2) | ((unsigned int)f_to_bf16(p3) << 16);
        }
        rsum += __shfl_xor(rsum, 16);
        rsum += __shfl_xor(rsum, 32);
        float inv = 1.f / rsum;   // lane (q, l15) holds inv for row i = t*16+l15

        // O = mfma(P, V^T): A-fragment built by cross-lane shuffle, B from Vs
        f32x4 o[4];
        #pragma unroll
        for (int dt = 0; dt < 4; ++dt) o[dt] = (f32x4){0.f, 0.f, 0.f, 0.f};
        #pragma unroll
        for (int kk = 0; kk < 7; ++kk) {
            int a0 = (int)pk0[2 * kk],     a1 = (int)pk1[2 * kk];
            int b0 = (int)pk0[2 * kk + 1], b1 = (int)pk1[2 * kk + 1];
            int w0a = __builtin_amdgcn_ds_bpermute(idx01, a0);
            int w0b = __builtin_amdgcn_ds_bpermute(idx01, b0);
            int w1a = __builtin_amdgcn_ds_bpermute(idx01, a1);
            int w1b = __builtin_amdgcn_ds_bpermute(idx01, b1);
            int w2a = __builtin_amdgcn_ds_bpermute(idx23, a0);
            int w2b = __builtin_amdgcn_ds_bpermute(idx23, b0);
            int w3a = __builtin_amdgcn_ds_bpermute(idx23, a1);
            int w3b = __builtin_amdgcn_ds_bpermute(idx23, b1);
            union { uint4 u; bf16x8 v; } pw;
            pw.u.x = (unsigned int)(lohalf ? w0a : w0b);   // j = kk*32+q*8+0,1
            pw.u.y = (unsigned int)(lohalf ? w1a : w1b);   // +2,3
            pw.u.z = (unsigned int)(lohalf ? w2a : w2b);   // +4,5
            pw.u.w = (unsigned int)(lohalf ? w3a : w3b);   // +6,7
            bf16x8 pf = pw.v;
            #pragma unroll
            for (int dt = 0; dt < 4; ++dt) {
                bf16x8 vfr = *(const bf16x8*)((const char*)Vs + (dt * 16 + l15) * 448 +
                                              ((kk * 64 + quad * 16) ^ ((l15 & 3) << 4)));
                o[dt] = __builtin_amdgcn_mfma_f32_16x16x32_bf16(pf, vfr, o[dt], 0, 0, 0);
            }
        }

        // store: row i = t*16 + quad*4 + r, col d = dt*16 + l15
        #pragma unroll
        for (int r = 0; r < 4; ++r) {
            int row = t * 16 + quad * 4 + r;
            if (row < 196) {
                float iv = __shfl(inv, quad * 4 + r);   // from lane l15 = quad*4+r
                unsigned short* dst = attn_out + ((size_t)(b * NTOK + row)) * CDIM + h * HDIM + l15;
                #pragma unroll
                for (int dt = 0; dt < 4; ++dt)
                    dst[dt * 16] = f_to_bf16(o[dt][r] * iv);
            }
        }
    }
}

// ------ GEMM2 (r10, 128x128) + XCD-chunked remap (588 = 8*73+4) -----------
__global__ __launch_bounds__(256) void gemm_proj(
        const unsigned short* __restrict__ A,   // [12544][768] bf16
        const unsigned short* __restrict__ W,   // [768][768] bf16
        const float* __restrict__ bias,         // (768,)
        float* __restrict__ out) {
    __shared__ __align__(16) unsigned short As[2][128 * 32];
    __shared__ __align__(16) unsigned short Bs[2][128 * 32];
    int tid = threadIdx.x;
    int l = blockIdx.y * 6 + blockIdx.x;
    int xcd = l & 7, idx = l >> 3;
    int t = (xcd < 4) ? xcd * 74 + idx : 296 + (xcd - 4) * 73 + idx;  // bijective
    int by = t / 6, bx = t - by * 6;
    int m0 = by * 128;
    int n0 = bx * 128;
    int w = tid >> 6, lane = tid & 63, l15 = lane & 15, quad = lane >> 4;
    int mw = (w & 1) * 64, nw = (w >> 1) * 64;

    const unsigned short* ga = A + (size_t)(m0 + (tid >> 2)) * CDIM + (tid & 3) * 8;
    const unsigned short* gb = W + (size_t)(n0 + (tid >> 2)) * CDIM + (tid & 3) * 8;

    f32x4 acc[4][4];
    #pragma unroll
    for (int i = 0; i < 4; ++i)
        #pragma unroll
        for (int j = 0; j < 4; ++j) acc[i][j] = (f32x4){0.f, 0.f, 0.f, 0.f};

    auto issue = [&](int buf) {
        gld16(ga, &As[buf][tid * 8]);
        gld16(ga + 64 * CDIM, &As[buf][2048 + tid * 8]);
        gld16(gb, &Bs[buf][tid * 8]);
        gld16(gb + 64 * CDIM, &Bs[buf][2048 + tid * 8]);
        ga += 32; gb += 32;
    };
    auto compute = [&](int buf) {
        bf16x8 af[4], bf[4];
        #pragma unroll
        for (int mt = 0; mt < 4; ++mt)
            af[mt] = *(const bf16x8*)&As[buf][(mw + mt * 16 + l15) * 32 + quad * 8];
        #pragma unroll
        for (int nt = 0; nt < 4; ++nt)
            bf[nt] = *(const bf16x8*)&Bs[buf][(nw + nt * 16 + l15) * 32 + quad * 8];
        #pragma unroll
        for (int mt = 0; mt < 4; ++mt)
            #pragma unroll
            for (int nt = 0; nt < 4; ++nt)
                acc[mt][nt] = __builtin_amdgcn_mfma_f32_16x16x32_bf16(bf[nt], af[mt], acc[mt][nt], 0, 0, 0);
    };

    issue(0);
    #pragma unroll 1
    for (int kt = 0; kt < 24; kt += 2) {
        __syncthreads();
        issue(1);
        compute(0);
        __syncthreads();
        if (kt + 2 < 24) issue(0);
        compute(1);
    }

    // swapped: regs span out-col c (4 consec), lanes span out-row m
    #pragma unroll
    for (int nt = 0; nt < 4; ++nt) {
        int c = n0 + nw + nt * 16 + quad * 4;
        float4 bv = *(const float4*)(bias + c);
        #pragma unroll
        for (int mt = 0; mt < 4; ++mt) {
            int m = m0 + mw + mt * 16 + l15;
            float4 ov;
            ov.x = acc[mt][nt][0] + bv.x;
            ov.y = acc[mt][nt][1] + bv.y;
            ov.z = acc[mt][nt][2] + bv.z;
            ov.w = acc[mt][nt][3] + bv.w;
            *(float4*)(out + (size_t)m * CDIM + c) = ov;
        }
    }
}

extern "C" void kernel_launch(void* const* d_in, const int* in_sizes, int n_in,
                              void* d_out, int out_size, void* d_ws, size_t ws_size,
                              hipStream_t stream) {
    const float* x      = (const float*)d_in[0];
    const float* qk_w   = (const float*)d_in[1];
    const float* v_w    = (const float*)d_in[2];
    const float* w1_w   = (const float*)d_in[3];
    const float* w1_b   = (const float*)d_in[4];
    const float* w2     = (const float*)d_in[5];
    const float* b2     = (const float*)d_in[6];
    const float* proj_w = (const float*)d_in[7];
    const float* proj_b = (const float*)d_in[8];
    float* out = (float*)d_out;

    // workspace layout (bf16 = unsigned short)
    unsigned short* x_bf  = (unsigned short*)d_ws;            // 9,633,792 elems
    unsigned short* w_cat = x_bf + 9633792;                   // 1,769,472
    unsigned short* pw_bf = w_cat + 1769472;                  //   589,824
    float* pm2            = (float*)(pw_bf + 589824);         //   460,992 f32
    unsigned short* qkv   = (unsigned short*)(pm2 + 460992);  // 30,277,632
    unsigned short* attn_o = x_bf;                            // alias (dead after gemm1)

    // 4 dispatches total: prep_all -> gemm_qkv_all -> attn -> proj
    prep_all<<<13513, 256, 0, stream>>>(x, qk_w, v_w, proj_w,
                                        w1_w, w1_b, w2, b2,
                                        x_bf, w_cat, pw_bf, pm2);

    dim3 gqkv(18, 98);
    gemm_qkv_all<<<gqkv, 256, 0, stream>>>(x_bf, w_cat, qkv);

    attn_mfma<<<768, 256, 0, stream>>>(qkv, pm2, attn_o);

    dim3 g2(6, 98);
    gemm_proj<<<g2, 256, 0, stream>>>(attn_o, pw_bf, proj_b, out);
}